// Round 5
// baseline (444.050 us; speedup 1.0000x reference)
//
#include <hip/hip_runtime.h>
#include <math.h>

#define SEQ    2048
#define NBATCH 4
#define NTOK   8192
#define EMB    768
#define DFF    3072
#define NH     8
#define HD     96
#define QSEG   6291456   // 32 pairs * 2048 * 96

typedef float            f32x4  __attribute__((ext_vector_type(4)));
typedef float            f32x16 __attribute__((ext_vector_type(16)));
typedef __bf16           bf16x8 __attribute__((ext_vector_type(8)));
typedef unsigned short   u16;
typedef unsigned int     u32;
typedef int              i32x2  __attribute__((ext_vector_type(2)));
typedef u16              u16x8  __attribute__((ext_vector_type(8)));
typedef u16              u16x4  __attribute__((ext_vector_type(4)));

__device__ __forceinline__ u16 f2bf(float f) {
  union { float f; unsigned u; } v; v.f = f;
  unsigned r = v.u + 0x7FFFu + ((v.u >> 16) & 1u);
  return (u16)(r >> 16);
}
__device__ __forceinline__ bf16x8 asbf(u16x8 v) { return __builtin_bit_cast(bf16x8, v); }
__device__ __forceinline__ u32 pk2(float a, float b) {
  union { __bf16 h[2]; u32 w; } u; u.h[0] = (__bf16)a; u.h[1] = (__bf16)b; return u.w;
}

__device__ __forceinline__ void gload16(const void* g, void* l) {
  __builtin_amdgcn_global_load_lds((const __attribute__((address_space(1))) unsigned*)g,
                                   (__attribute__((address_space(3))) unsigned*)l, 16, 0, 0);
}

// ---------------------------------------------------------------------------
// Generic fp32 [R][C] -> bf16 transposed [C][R] (weights -> B^T bf16)
// ---------------------------------------------------------------------------
__global__ __launch_bounds__(256)
void transpose_cvt(const float* __restrict__ in, u16* __restrict__ out, int R, int C) {
  __shared__ float tile[32][33];
  const int c0 = blockIdx.x * 32, r0 = blockIdx.y * 32;
  const int tr = threadIdx.x >> 5, tc = threadIdx.x & 31;
#pragma unroll
  for (int i = 0; i < 4; ++i)
    tile[tr + 8 * i][tc] = in[(size_t)(r0 + tr + 8 * i) * C + c0 + tc];
  __syncthreads();
#pragma unroll
  for (int i = 0; i < 4; ++i)
    out[(size_t)(c0 + tr + 8 * i) * R + r0 + tc] = f2bf(tile[tc][tr + 8 * i]);
}

__global__ __launch_bounds__(256)
void concat_bias(const float* __restrict__ bq, const float* __restrict__ bk,
                 const float* __restrict__ bv, float* __restrict__ out) {
  int i = blockIdx.x * 256 + threadIdx.x;
  if (i < 2304) {
    const float* s = (i < 768) ? bq : ((i < 1536) ? bk : bv);
    out[i] = s[i % 768];
  }
}

// ---------------------------------------------------------------------------
// LayerNorm: fp32 [rows][768] -> bf16 [rows][768]; one wave per row
// ---------------------------------------------------------------------------
__global__ __launch_bounds__(256)
void ln_k(const float* __restrict__ x, const float* __restrict__ g,
          const float* __restrict__ b, u16* __restrict__ y) {
  const int row = blockIdx.x * 4 + (threadIdx.x >> 6);
  const int l = threadIdx.x & 63;
  const float* xr = x + (size_t)row * EMB;
  f32x4 v[3];
#pragma unroll
  for (int i = 0; i < 3; ++i) v[i] = *(const f32x4*)(xr + (l + 64 * i) * 4);
  float s = 0.f;
#pragma unroll
  for (int i = 0; i < 3; ++i)
#pragma unroll
    for (int j = 0; j < 4; ++j) s += v[i][j];
#pragma unroll
  for (int m = 32; m; m >>= 1) s += __shfl_xor(s, m, 64);
  const float mu = s * (1.0f / EMB);
  float q = 0.f;
#pragma unroll
  for (int i = 0; i < 3; ++i)
#pragma unroll
    for (int j = 0; j < 4; ++j) { float d = v[i][j] - mu; q += d * d; }
#pragma unroll
  for (int m = 32; m; m >>= 1) q += __shfl_xor(q, m, 64);
  const float rstd = rsqrtf(q * (1.0f / EMB) + 1e-5f);
#pragma unroll
  for (int i = 0; i < 3; ++i) {
    const int c0 = (l + 64 * i) * 4;
    f32x4 gv = *(const f32x4*)(g + c0);
    f32x4 bv = *(const f32x4*)(b + c0);
    u16x4 o;
#pragma unroll
    for (int j = 0; j < 4; ++j) o[j] = f2bf((v[i][j] - mu) * rstd * gv[j] + bv[j]);
    *(u16x4*)(y + (size_t)row * EMB + c0) = o;
  }
}

// ---------------------------------------------------------------------------
// GEMM: C[M][N] = A[M][K](bf16) @ B^T[N][K](bf16) + epilogue
// EPI 0: +bias, scatter bf16 to qkv layout (Q,K: [p][tok][d]; V: [p][d][tok])
// EPI 1: +bias +resid -> fp32
// EPI 2: +bias, exact GELU -> bf16
// EPI 3: +bias +resid -> fp32
// 128x128 tile, BK=32, 4 waves. Depth-1 pipelined K-loop (T3-minimum):
// LDS double-buffer, STAGE(t+1) issued before compute(t), counted vmcnt(4)
// (never 0 mid-loop), raw s_barrier (no implicit full drain).
// ---------------------------------------------------------------------------
template <int EPI>
__global__ __launch_bounds__(256, 4)
void gemm_k(const u16* __restrict__ A, const u16* __restrict__ BT,
            const float* __restrict__ bias, const float* __restrict__ resid,
            void* __restrict__ outp, int M, int N, int K, int nbn) {
  __shared__ __align__(16) u16 sA[2][128 * 32];
  __shared__ __align__(16) u16 sB[2][128 * 32];
  const int t = threadIdx.x;
  const int w = t >> 6, l = t & 63;
  const int wr = w >> 1, wc = w & 1;
  const int lr = l & 15, lg = l >> 4;
  const int cpx = gridDim.x >> 3;
  const int bid = (blockIdx.x & 7) * cpx + (blockIdx.x >> 3);
  const int bm = bid / nbn, bn = bid % nbn;
  const int m0 = bm << 7, n0 = bn << 7;

  const int r0 = t >> 2;
  const int cL = t & 3;
  const int cG0 = cL ^ ((r0 >> 1) & 3);
  const int cG1 = cL ^ (((r0 + 64) >> 1) & 3);
  const u16* gA0 = A + (size_t)(m0 + r0) * K + cG0 * 8;
  const u16* gA1 = A + (size_t)(m0 + r0 + 64) * K + cG1 * 8;
  const u16* gB0 = BT + (size_t)(n0 + r0) * K + cG0 * 8;
  const u16* gB1 = BT + (size_t)(n0 + r0 + 64) * K + cG1 * 8;

#define GSTAGE(bi, kel) {                      \
    gload16(gA0 + (kel), &sA[bi][t * 8]);      \
    gload16(gA1 + (kel), &sA[bi][2048 + t * 8]); \
    gload16(gB0 + (kel), &sB[bi][t * 8]);      \
    gload16(gB1 + (kel), &sB[bi][2048 + t * 8]); }

  f32x4 acc[4][4] = {};
  const int swz = (lr >> 1) & 3;

  GSTAGE(0, 0);
  int cur = 0;
  for (int kt = 0; kt < K; kt += 32) {
    __builtin_amdgcn_sched_barrier(0);
    __builtin_amdgcn_s_barrier();           // (a) readers of buf cur^1 done
    if (kt + 32 < K) {
      GSTAGE(cur ^ 1, kt + 32);             // next tile in flight over compute
      asm volatile("s_waitcnt vmcnt(4)" ::: "memory");  // wait only tile-t loads
    } else {
      asm volatile("s_waitcnt vmcnt(0)" ::: "memory");
    }
    __builtin_amdgcn_s_barrier();           // (b) buf cur complete for all waves
    __builtin_amdgcn_sched_barrier(0);
    bf16x8 af[4], bfr[4];
#pragma unroll
    for (int mf = 0; mf < 4; ++mf) {
      int r = wr * 64 + mf * 16 + lr;
      af[mf] = asbf(*(const u16x8*)(&sA[cur][r * 32 + ((lg ^ swz) * 8)]));
    }
#pragma unroll
    for (int nf = 0; nf < 4; ++nf) {
      int r = wc * 64 + nf * 16 + lr;
      bfr[nf] = asbf(*(const u16x8*)(&sB[cur][r * 32 + ((lg ^ swz) * 8)]));
    }
#pragma unroll
    for (int mf = 0; mf < 4; ++mf)
#pragma unroll
      for (int nf = 0; nf < 4; ++nf)
        acc[mf][nf] = __builtin_amdgcn_mfma_f32_16x16x32_bf16(af[mf], bfr[nf], acc[mf][nf], 0, 0, 0);
    cur ^= 1;
  }
#undef GSTAGE

  // epilogue: C/D layout col=lane&15, row=(lane>>4)*4+j  [m89/m91 verified]
#pragma unroll
  for (int nf = 0; nf < 4; ++nf) {
    const int col = n0 + wc * 64 + nf * 16 + lr;
    const float bcol = bias[col];
    if (EPI == 0) {
      const int which = col / 768;
      const int cm = col - which * 768;
      const int h = cm / 96;
      const int d = cm - h * 96;
      if (which < 2) {
        u16* qb = (u16*)outp + (size_t)which * QSEG;
#pragma unroll
        for (int mf = 0; mf < 4; ++mf)
#pragma unroll
          for (int j = 0; j < 4; ++j) {
            const int row = m0 + wr * 64 + mf * 16 + lg * 4 + j;
            const int b = row >> 11, tok = row & 2047;
            qb[((size_t)((b * NH + h) * SEQ + tok)) * HD + d] = f2bf(acc[mf][nf][j] + bcol);
          }
      } else {  // V -> V^T layout [pair][d][tok]; tok j-contiguous -> u16x4
        u16* vbp = (u16*)outp + 2 * (size_t)QSEG;
#pragma unroll
        for (int mf = 0; mf < 4; ++mf) {
          const int row = m0 + wr * 64 + mf * 16 + lg * 4;
          const int b = row >> 11, tok = row & 2047;
          u16x4 o4;
#pragma unroll
          for (int j = 0; j < 4; ++j) o4[j] = f2bf(acc[mf][nf][j] + bcol);
          *(u16x4*)(vbp + ((size_t)((b * NH + h) * HD + d)) * SEQ + tok) = o4;
        }
      }
    } else {
#pragma unroll
      for (int mf = 0; mf < 4; ++mf)
#pragma unroll
        for (int j = 0; j < 4; ++j) {
          const int row = m0 + wr * 64 + mf * 16 + lg * 4 + j;
          const float v = acc[mf][nf][j] + bcol;
          const size_t off = (size_t)row * N + col;
          if (EPI == 1 || EPI == 3) {
            ((float*)outp)[off] = v + resid[off];
          } else {
            ((u16*)outp)[off] = f2bf(0.5f * v * (1.0f + erff(v * 0.70710678f)));
          }
        }
    }
  }
}

// ---------------------------------------------------------------------------
// Flash attention, 8-warp swapped 32x32 structure (m214-style).
// Q,K = [32 pairs][2048][96] bf16; V = [32 pairs][96][2048] bf16 (V^T).
// S^T = mfma_32x32x16(K, Q); softmax in-register; P via pk2+permlane32_swap;
// O^T = mfma_32x32x16(V^T, P^T). Defer-max (T13). Depth-1 staged K/V dbuf.
// ---------------------------------------------------------------------------
__global__ __launch_bounds__(512, 2)
void attn_k(const u16* __restrict__ qkv, u16* __restrict__ obuf) {
  __shared__ __align__(16) u16 sK[2][64 * 128];  // 64 rows x 16 chunks (12 real)
  __shared__ __align__(16) u16 sV[2][128 * 64];  // 128 rows (96 real) x 8 chunks
  const int bid = blockIdx.x;
  const int x = bid & 7, i = bid >> 3;           // XCD x owns pairs 4x..4x+3
  const int p = x * 4 + (i & 3), qt = i >> 2;
  const int t = threadIdx.x;
  const int w = t >> 6, l = t & 63;
  const int hl = l >> 5, lm = l & 31;
  const u16* qb  = qkv + (size_t)p * SEQ * HD;
  const u16* kb  = qb + QSEG;
  const u16* vtb = qkv + 2 * (size_t)QSEG + (size_t)p * SEQ * HD;
  const int q0w = qt * 256 + w * 32;

  // Q frags (B-operand: n=q=lm, k=d): held in registers whole kernel
  bf16x8 qf[6];
#pragma unroll
  for (int ds = 0; ds < 6; ++ds)
    qf[ds] = asbf(*(const u16x8*)(qb + (size_t)(q0w + lm) * HD + ds * 16 + hl * 8));

  // staging source offsets (pre-swizzled global, linear LDS dest)
  const int rK0 = t >> 4,        ccK0 = (t & 15) ^ (rK0 & 7);
  const int rK1 = 32 + (t >> 4), ccK1 = (t & 15) ^ (rK1 & 7);
  const int koff0 = rK0 * HD + ccK0 * 8;
  const int koff1 = rK1 * HD + ccK1 * 8;
  const int rV0 = t >> 3,        ccV0 = (t & 7) ^ (rV0 & 7);
  const int rV1 = 64 + (t >> 3), ccV1 = (t & 7) ^ (rV1 & 7);
  const int voff0 = rV0 * SEQ + ccV0 * 8;
  const int voff1 = rV1 * SEQ + ccV1 * 8;

#define ASTAGE(bi, kt_) {                                            \
    const u16* kbase = kb + (size_t)(kt_) * 64 * HD;                 \
    gload16(kbase + koff0, &sK[bi][t * 8]);                          \
    gload16(kbase + koff1, &sK[bi][4096 + t * 8]);                   \
    const u16* vbase = vtb + (kt_) * 64;                             \
    gload16(vbase + voff0, &sV[bi][t * 8]);                          \
    gload16(vbase + voff1, &sV[bi][4096 + t * 8]); }

  f32x16 oacc[3] = {};
  float mreg = -1e30f, lsum = 0.f;
  int cur = 0;

  ASTAGE(0, 0);
  for (int kt = 0; kt < 32; ++kt) {
    asm volatile("s_waitcnt vmcnt(0)" ::: "memory");
    __syncthreads();
    if (kt < 31) ASTAGE(cur ^ 1, kt + 1);

    // S^T = K @ Q  (lane: q=lm; rows kv = tile*32 + (r&3)+8*(r>>2)+4*hl)
    f32x16 st[2] = {};
#pragma unroll
    for (int tile = 0; tile < 2; ++tile)
#pragma unroll
      for (int ds = 0; ds < 6; ++ds) {
        const int row = tile * 32 + lm;
        const int cs = (2 * ds + hl) ^ (l & 7);
        bf16x8 kf = asbf(*(const u16x8*)(&sK[cur][row * 128 + cs * 8]));
        st[tile] = __builtin_amdgcn_mfma_f32_32x32x16_bf16(kf, qf[ds], st[tile], 0, 0, 0);
      }

    // in-register online softmax (row is lane-local + partner half)
    float pmax = st[0][0];
#pragma unroll
    for (int r = 1; r < 16; ++r) pmax = fmaxf(pmax, st[0][r]);
#pragma unroll
    for (int r = 0; r < 16; ++r) pmax = fmaxf(pmax, st[1][r]);
    pmax = fmaxf(pmax, __shfl_xor(pmax, 32, 64));
    if (__any(pmax > mreg + 8.f)) {   // defer-max (T13)
      const float mn = fmaxf(mreg, pmax);
      const float al = __expf(mreg - mn);
      mreg = mn; lsum *= al;
#pragma unroll
      for (int d3 = 0; d3 < 3; ++d3)
#pragma unroll
        for (int r = 0; r < 16; ++r) oacc[d3][r] *= al;
    }
    float ts = 0.f;
    u32 wds[16];
#pragma unroll
    for (int g = 0; g < 8; ++g) {
      const float e0 = __expf(st[(4 * g) >> 4][(4 * g) & 15] - mreg);
      const float e1 = __expf(st[(4 * g + 1) >> 4][(4 * g + 1) & 15] - mreg);
      const float e2 = __expf(st[(4 * g + 2) >> 4][(4 * g + 2) & 15] - mreg);
      const float e3 = __expf(st[(4 * g + 3) >> 4][(4 * g + 3) & 15] - mreg);
      ts += (e0 + e1) + (e2 + e3);
      wds[2 * g]     = pk2(e0, e1);
      wds[2 * g + 1] = pk2(e2, e3);
    }
    ts += __shfl_xor(ts, 32, 64);
    lsum += ts;

    // O^T += V^T @ P^T ; P B-frag for step s = p[8s..8s+7] via 2 swaps
#pragma unroll
    for (int s = 0; s < 4; ++s) {
      i32x2 r02 = __builtin_amdgcn_permlane32_swap((int)wds[4 * s], (int)wds[4 * s + 2], false, false);
      i32x2 r13 = __builtin_amdgcn_permlane32_swap((int)wds[4 * s + 1], (int)wds[4 * s + 3], false, false);
      union { u32 wu[4]; bf16x8 v; } pu;
      pu.wu[0] = (u32)r02[0]; pu.wu[1] = (u32)r13[0];
      pu.wu[2] = (u32)r02[1]; pu.wu[3] = (u32)r13[1];
      const bf16x8 pf = pu.v;
#pragma unroll
      for (int d3 = 0; d3 < 3; ++d3) {
        const int row = d3 * 32 + lm;
        const int cs = (2 * s + hl) ^ (l & 7);
        bf16x8 vf = asbf(*(const u16x8*)(&sV[cur][row * 64 + cs * 8]));
        oacc[d3] = __builtin_amdgcn_mfma_f32_32x32x16_bf16(vf, pf, oacc[d3], 0, 0, 0);
      }
    }
    cur ^= 1;
  }

  // epilogue: O^T[d][q] -> obuf[b][tok][h*96+d], scaled by 1/(lsum*sqrt(768))
  const int b = p >> 3, h = p & 7;
  const float sc = 0.03608439182435161f / lsum;
  u16* ob = obuf + (size_t)(b * SEQ + q0w + lm) * EMB + h * HD;
#pragma unroll
  for (int d3 = 0; d3 < 3; ++d3)
#pragma unroll
    for (int g = 0; g < 4; ++g) {
      u16x4 o4;
#pragma unroll
      for (int j = 0; j < 4; ++j) o4[j] = f2bf(oacc[d3][4 * g + j] * sc);
      *(u16x4*)(ob + d3 * 32 + 8 * g + 4 * hl) = o4;
    }
#undef ASTAGE
}

// ---------------------------------------------------------------------------
extern "C" void kernel_launch(void* const* d_in, const int* in_sizes, int n_in,
                              void* d_out, int out_size, void* d_ws, size_t ws_size,
                              hipStream_t stream) {
  const float* x    = (const float*)d_in[0];
  const float* ln1g = (const float*)d_in[1];
  const float* ln1b = (const float*)d_in[2];
  const float* wq   = (const float*)d_in[3];
  const float* bq   = (const float*)d_in[4];
  const float* wk   = (const float*)d_in[5];
  const float* bk   = (const float*)d_in[6];
  const float* wv   = (const float*)d_in[7];
  const float* bv   = (const float*)d_in[8];
  const float* wo   = (const float*)d_in[9];
  const float* bo   = (const float*)d_in[10];
  const float* ln2g = (const float*)d_in[11];
  const float* ln2b = (const float*)d_in[12];
  const float* w1   = (const float*)d_in[13];
  const float* b1   = (const float*)d_in[14];
  const float* w2   = (const float*)d_in[15];
  const float* b2   = (const float*)d_in[16];
  float* out = (float*)d_out;

  char* ws = (char*)d_ws;
  u16* wqkvT  = (u16*)ws;   ws += (size_t)2304 * 768 * 2;
  u16* woT    = (u16*)ws;   ws += (size_t)768 * 768 * 2;
  u16* w1T    = (u16*)ws;   ws += (size_t)3072 * 768 * 2;
  u16* w2T    = (u16*)ws;   ws += (size_t)768 * 3072 * 2;
  float* bqkv = (float*)ws; ws += (size_t)2304 * 4;
  u16* bufA   = (u16*)ws;   ws += (size_t)NTOK * EMB * 2;   // y -> o -> z
  u16* bigbuf = (u16*)ws;   ws += (size_t)NTOK * DFF * 2;   // qkv -> ffn hidden
  float* x1   = (float*)ws; ws += (size_t)NTOK * EMB * 4;

  transpose_cvt<<<dim3(24, 24), 256, 0, stream>>>(wq, wqkvT, 768, 768);
  transpose_cvt<<<dim3(24, 24), 256, 0, stream>>>(wk, wqkvT + 768 * 768, 768, 768);
  transpose_cvt<<<dim3(24, 24), 256, 0, stream>>>(wv, wqkvT + 2 * 768 * 768, 768, 768);
  transpose_cvt<<<dim3(24, 24), 256, 0, stream>>>(wo, woT, 768, 768);
  transpose_cvt<<<dim3(96, 24), 256, 0, stream>>>(w1, w1T, 768, 3072);
  transpose_cvt<<<dim3(24, 96), 256, 0, stream>>>(w2, w2T, 3072, 768);
  concat_bias<<<9, 256, 0, stream>>>(bq, bk, bv, bqkv);

  ln_k<<<NTOK / 4, 256, 0, stream>>>(x, ln1g, ln1b, bufA);
  gemm_k<0><<<64 * 18, 256, 0, stream>>>(bufA, wqkvT, bqkv, nullptr, bigbuf,
                                         NTOK, 2304, 768, 18);
  attn_k<<<256, 512, 0, stream>>>(bigbuf, bufA);
  gemm_k<1><<<64 * 6, 256, 0, stream>>>(bufA, woT, bo, x, x1, NTOK, 768, 768, 6);
  ln_k<<<NTOK / 4, 256, 0, stream>>>(x1, ln2g, ln2b, bufA);
  gemm_k<2><<<64 * 24, 256, 0, stream>>>(bufA, w1T, b1, nullptr, bigbuf,
                                         NTOK, 3072, 768, 24);
  gemm_k<3><<<64 * 6, 256, 0, stream>>>(bigbuf, w2T, b2, x1, out, NTOK, 768, 3072, 6);
}

// Round 6
// 412.225 us; speedup vs baseline: 1.0772x; 1.0772x over previous
//
#include <hip/hip_runtime.h>
#include <math.h>

#define SEQ    2048
#define NBATCH 4
#define NTOK   8192
#define EMB    768
#define DFF    3072
#define NH     8
#define HD     96
#define QSEG   6291456   // 32 pairs * 2048 * 96

typedef float            f32x4  __attribute__((ext_vector_type(4)));
typedef float            f32x16 __attribute__((ext_vector_type(16)));
typedef __bf16           bf16x8 __attribute__((ext_vector_type(8)));
typedef unsigned short   u16;
typedef unsigned int     u32;
typedef int              i32x2  __attribute__((ext_vector_type(2)));
typedef u16              u16x8  __attribute__((ext_vector_type(8)));
typedef u16              u16x4  __attribute__((ext_vector_type(4)));

__device__ __forceinline__ u16 f2bf(float f) {
  union { float f; unsigned u; } v; v.f = f;
  unsigned r = v.u + 0x7FFFu + ((v.u >> 16) & 1u);
  return (u16)(r >> 16);
}
__device__ __forceinline__ bf16x8 asbf(u16x8 v) { return __builtin_bit_cast(bf16x8, v); }
__device__ __forceinline__ u32 pk2(float a, float b) {
  union { __bf16 h[2]; u32 w; } u; u.h[0] = (__bf16)a; u.h[1] = (__bf16)b; return u.w;
}

__device__ __forceinline__ void gload16(const void* g, void* l) {
  __builtin_amdgcn_global_load_lds((const __attribute__((address_space(1))) unsigned*)g,
                                   (__attribute__((address_space(3))) unsigned*)l, 16, 0, 0);
}

// ---------------------------------------------------------------------------
// Generic fp32 [R][C] -> bf16 transposed [C][R] (weights -> B^T bf16)
// ---------------------------------------------------------------------------
__global__ __launch_bounds__(256)
void transpose_cvt(const float* __restrict__ in, u16* __restrict__ out, int R, int C) {
  __shared__ float tile[32][33];
  const int c0 = blockIdx.x * 32, r0 = blockIdx.y * 32;
  const int tr = threadIdx.x >> 5, tc = threadIdx.x & 31;
#pragma unroll
  for (int i = 0; i < 4; ++i)
    tile[tr + 8 * i][tc] = in[(size_t)(r0 + tr + 8 * i) * C + c0 + tc];
  __syncthreads();
#pragma unroll
  for (int i = 0; i < 4; ++i)
    out[(size_t)(c0 + tr + 8 * i) * R + r0 + tc] = f2bf(tile[tc][tr + 8 * i]);
}

__global__ __launch_bounds__(256)
void concat_bias(const float* __restrict__ bq, const float* __restrict__ bk,
                 const float* __restrict__ bv, float* __restrict__ out) {
  int i = blockIdx.x * 256 + threadIdx.x;
  if (i < 2304) {
    const float* s = (i < 768) ? bq : ((i < 1536) ? bk : bv);
    out[i] = s[i % 768];
  }
}

// ---------------------------------------------------------------------------
// LayerNorm: fp32 [rows][768] -> bf16 [rows][768]; one wave per row
// ---------------------------------------------------------------------------
__global__ __launch_bounds__(256)
void ln_k(const float* __restrict__ x, const float* __restrict__ g,
          const float* __restrict__ b, u16* __restrict__ y) {
  const int row = blockIdx.x * 4 + (threadIdx.x >> 6);
  const int l = threadIdx.x & 63;
  const float* xr = x + (size_t)row * EMB;
  f32x4 v[3];
#pragma unroll
  for (int i = 0; i < 3; ++i) v[i] = *(const f32x4*)(xr + (l + 64 * i) * 4);
  float s = 0.f;
#pragma unroll
  for (int i = 0; i < 3; ++i)
#pragma unroll
    for (int j = 0; j < 4; ++j) s += v[i][j];
#pragma unroll
  for (int m = 32; m; m >>= 1) s += __shfl_xor(s, m, 64);
  const float mu = s * (1.0f / EMB);
  float q = 0.f;
#pragma unroll
  for (int i = 0; i < 3; ++i)
#pragma unroll
    for (int j = 0; j < 4; ++j) { float d = v[i][j] - mu; q += d * d; }
#pragma unroll
  for (int m = 32; m; m >>= 1) q += __shfl_xor(q, m, 64);
  const float rstd = rsqrtf(q * (1.0f / EMB) + 1e-5f);
#pragma unroll
  for (int i = 0; i < 3; ++i) {
    const int c0 = (l + 64 * i) * 4;
    f32x4 gv = *(const f32x4*)(g + c0);
    f32x4 bv = *(const f32x4*)(b + c0);
    u16x4 o;
#pragma unroll
    for (int j = 0; j < 4; ++j) o[j] = f2bf((v[i][j] - mu) * rstd * gv[j] + bv[j]);
    *(u16x4*)(y + (size_t)row * EMB + c0) = o;
  }
}

// ---------------------------------------------------------------------------
// GEMM: C[M][N] = A[M][K](bf16) @ B^T[N][K](bf16) + epilogue
// EPI 0: +bias, scatter bf16 to qkv layout (Q,K: [p][tok][d]; V: [p][d][tok])
// EPI 1: +bias +resid -> fp32
// EPI 2: +bias, exact GELU -> bf16
// EPI 3: +bias +resid -> fp32
// 128x128 tile, BK=32, 4 waves. Depth-2 pipelined K-loop: TRIPLE-buffered LDS,
// stage(t+2) issued at iteration t, counted vmcnt(8) (tile-t loads are the
// oldest 4 of <=12 outstanding -> ~2 iterations of latency slack). Raw
// s_barrier (no vmcnt(0) drain); NO sched_barrier pins (m141/R5 lesson).
// Tail peeled: vmcnt(4), vmcnt(0).
// ---------------------------------------------------------------------------
template <int EPI>
__global__ __launch_bounds__(256, 3)
void gemm_k(const u16* __restrict__ A, const u16* __restrict__ BT,
            const float* __restrict__ bias, const float* __restrict__ resid,
            void* __restrict__ outp, int M, int N, int K, int nbn) {
  __shared__ __align__(16) u16 sA[3][128 * 32];
  __shared__ __align__(16) u16 sB[3][128 * 32];
  const int t = threadIdx.x;
  const int w = t >> 6, l = t & 63;
  const int wr = w >> 1, wc = w & 1;
  const int lr = l & 15, lg = l >> 4;
  const int cpx = gridDim.x >> 3;
  const int bid = (blockIdx.x & 7) * cpx + (blockIdx.x >> 3);
  const int bm = bid / nbn, bn = bid % nbn;
  const int m0 = bm << 7, n0 = bn << 7;

  const int r0 = t >> 2;
  const int cL = t & 3;
  const int cG0 = cL ^ ((r0 >> 1) & 3);
  const int cG1 = cL ^ (((r0 + 64) >> 1) & 3);
  const u16* gA0 = A + (size_t)(m0 + r0) * K + cG0 * 8;
  const u16* gA1 = A + (size_t)(m0 + r0 + 64) * K + cG1 * 8;
  const u16* gB0 = BT + (size_t)(n0 + r0) * K + cG0 * 8;
  const u16* gB1 = BT + (size_t)(n0 + r0 + 64) * K + cG1 * 8;

#define GSTAGE(bi, kel) {                        \
    gload16(gA0 + (kel), &sA[bi][t * 8]);        \
    gload16(gA1 + (kel), &sA[bi][2048 + t * 8]); \
    gload16(gB0 + (kel), &sB[bi][t * 8]);        \
    gload16(gB1 + (kel), &sB[bi][2048 + t * 8]); }

#define GCOMPUTE(bi) {                                                         \
    bf16x8 af[4], bfr[4];                                                      \
    _Pragma("unroll")                                                          \
    for (int mf = 0; mf < 4; ++mf) {                                           \
      int r = wr * 64 + mf * 16 + lr;                                          \
      af[mf] = asbf(*(const u16x8*)(&sA[bi][r * 32 + ((lg ^ swz) * 8)]));      \
    }                                                                          \
    _Pragma("unroll")                                                          \
    for (int nf = 0; nf < 4; ++nf) {                                           \
      int r = wc * 64 + nf * 16 + lr;                                          \
      bfr[nf] = asbf(*(const u16x8*)(&sB[bi][r * 32 + ((lg ^ swz) * 8)]));     \
    }                                                                          \
    _Pragma("unroll")                                                          \
    for (int mf = 0; mf < 4; ++mf)                                             \
      _Pragma("unroll")                                                        \
      for (int nf = 0; nf < 4; ++nf)                                           \
        acc[mf][nf] = __builtin_amdgcn_mfma_f32_16x16x32_bf16(af[mf], bfr[nf], acc[mf][nf], 0, 0, 0); }

  f32x4 acc[4][4] = {};
  const int swz = (lr >> 1) & 3;

  GSTAGE(0, 0);
  GSTAGE(1, 32);
  int cur = 0;
  for (int kt = 0; kt + 64 < K; kt += 32) {
    __builtin_amdgcn_s_barrier();                       // readers of stage buf done
    int nxt = cur + 2; if (nxt >= 3) nxt -= 3;
    GSTAGE(nxt, kt + 64);                               // depth-2 prefetch
    asm volatile("s_waitcnt vmcnt(8)" ::: "memory");    // tile-kt loads landed
    __builtin_amdgcn_s_barrier();                       // all waves' quarters in
    GCOMPUTE(cur);
    ++cur; if (cur >= 3) cur -= 3;
  }
  // tail: tiles K-64, K-32 already staged
  __builtin_amdgcn_s_barrier();
  asm volatile("s_waitcnt vmcnt(4)" ::: "memory");
  __builtin_amdgcn_s_barrier();
  GCOMPUTE(cur);
  ++cur; if (cur >= 3) cur -= 3;
  __builtin_amdgcn_s_barrier();
  asm volatile("s_waitcnt vmcnt(0)" ::: "memory");
  __builtin_amdgcn_s_barrier();
  GCOMPUTE(cur);
#undef GSTAGE
#undef GCOMPUTE

  // epilogue: C/D layout col=lane&15, row=(lane>>4)*4+j  [m89/m91 verified]
#pragma unroll
  for (int nf = 0; nf < 4; ++nf) {
    const int col = n0 + wc * 64 + nf * 16 + lr;
    const float bcol = bias[col];
    if (EPI == 0) {
      const int which = col / 768;
      const int cm = col - which * 768;
      const int h = cm / 96;
      const int d = cm - h * 96;
      if (which < 2) {
        u16* qb = (u16*)outp + (size_t)which * QSEG;
#pragma unroll
        for (int mf = 0; mf < 4; ++mf)
#pragma unroll
          for (int j = 0; j < 4; ++j) {
            const int row = m0 + wr * 64 + mf * 16 + lg * 4 + j;
            const int b = row >> 11, tok = row & 2047;
            qb[((size_t)((b * NH + h) * SEQ + tok)) * HD + d] = f2bf(acc[mf][nf][j] + bcol);
          }
      } else {  // V -> V^T layout [pair][d][tok]; tok j-contiguous -> u16x4
        u16* vbp = (u16*)outp + 2 * (size_t)QSEG;
#pragma unroll
        for (int mf = 0; mf < 4; ++mf) {
          const int row = m0 + wr * 64 + mf * 16 + lg * 4;
          const int b = row >> 11, tok = row & 2047;
          u16x4 o4;
#pragma unroll
          for (int j = 0; j < 4; ++j) o4[j] = f2bf(acc[mf][nf][j] + bcol);
          *(u16x4*)(vbp + ((size_t)((b * NH + h) * HD + d)) * SEQ + tok) = o4;
        }
      }
    } else {
#pragma unroll
      for (int mf = 0; mf < 4; ++mf)
#pragma unroll
        for (int j = 0; j < 4; ++j) {
          const int row = m0 + wr * 64 + mf * 16 + lg * 4 + j;
          const float v = acc[mf][nf][j] + bcol;
          const size_t off = (size_t)row * N + col;
          if (EPI == 1 || EPI == 3) {
            ((float*)outp)[off] = v + resid[off];
          } else {
            ((u16*)outp)[off] = f2bf(0.5f * v * (1.0f + erff(v * 0.70710678f)));
          }
        }
    }
  }
}

// ---------------------------------------------------------------------------
// Flash attention, 8-warp swapped 32x32 structure (m214-style).
// Q,K = [32 pairs][2048][96] bf16; V = [32 pairs][96][2048] bf16 (V^T).
// S^T = mfma_32x32x16(K, Q); softmax in-register; P via pk2+permlane32_swap;
// O^T = mfma_32x32x16(V^T, P^T). Defer-max (T13). Depth-1 staged K/V dbuf.
// ---------------------------------------------------------------------------
__global__ __launch_bounds__(512, 2)
void attn_k(const u16* __restrict__ qkv, u16* __restrict__ obuf) {
  __shared__ __align__(16) u16 sK[2][64 * 128];  // 64 rows x 16 chunks (12 real)
  __shared__ __align__(16) u16 sV[2][128 * 64];  // 128 rows (96 real) x 8 chunks
  const int bid = blockIdx.x;
  const int x = bid & 7, i = bid >> 3;           // XCD x owns pairs 4x..4x+3
  const int p = x * 4 + (i & 3), qt = i >> 2;
  const int t = threadIdx.x;
  const int w = t >> 6, l = t & 63;
  const int hl = l >> 5, lm = l & 31;
  const u16* qb  = qkv + (size_t)p * SEQ * HD;
  const u16* kb  = qb + QSEG;
  const u16* vtb = qkv + 2 * (size_t)QSEG + (size_t)p * SEQ * HD;
  const int q0w = qt * 256 + w * 32;

  // Q frags (B-operand: n=q=lm, k=d): held in registers whole kernel
  bf16x8 qf[6];
#pragma unroll
  for (int ds = 0; ds < 6; ++ds)
    qf[ds] = asbf(*(const u16x8*)(qb + (size_t)(q0w + lm) * HD + ds * 16 + hl * 8));

  // staging source offsets (pre-swizzled global, linear LDS dest)
  const int rK0 = t >> 4,        ccK0 = (t & 15) ^ (rK0 & 7);
  const int rK1 = 32 + (t >> 4), ccK1 = (t & 15) ^ (rK1 & 7);
  const int koff0 = rK0 * HD + ccK0 * 8;
  const int koff1 = rK1 * HD + ccK1 * 8;
  const int rV0 = t >> 3,        ccV0 = (t & 7) ^ (rV0 & 7);
  const int rV1 = 64 + (t >> 3), ccV1 = (t & 7) ^ (rV1 & 7);
  const int voff0 = rV0 * SEQ + ccV0 * 8;
  const int voff1 = rV1 * SEQ + ccV1 * 8;

#define ASTAGE(bi, kt_) {                                            \
    const u16* kbase = kb + (size_t)(kt_) * 64 * HD;                 \
    gload16(kbase + koff0, &sK[bi][t * 8]);                          \
    gload16(kbase + koff1, &sK[bi][4096 + t * 8]);                   \
    const u16* vbase = vtb + (kt_) * 64;                             \
    gload16(vbase + voff0, &sV[bi][t * 8]);                          \
    gload16(vbase + voff1, &sV[bi][4096 + t * 8]); }

  f32x16 oacc[3] = {};
  float mreg = -1e30f, lsum = 0.f;
  int cur = 0;

  ASTAGE(0, 0);
  for (int kt = 0; kt < 32; ++kt) {
    asm volatile("s_waitcnt vmcnt(0)" ::: "memory");
    __syncthreads();
    if (kt < 31) ASTAGE(cur ^ 1, kt + 1);

    // S^T = K @ Q  (lane: q=lm; rows kv = tile*32 + (r&3)+8*(r>>2)+4*hl)
    f32x16 st[2] = {};
#pragma unroll
    for (int tile = 0; tile < 2; ++tile)
#pragma unroll
      for (int ds = 0; ds < 6; ++ds) {
        const int row = tile * 32 + lm;
        const int cs = (2 * ds + hl) ^ (l & 7);
        bf16x8 kf = asbf(*(const u16x8*)(&sK[cur][row * 128 + cs * 8]));
        st[tile] = __builtin_amdgcn_mfma_f32_32x32x16_bf16(kf, qf[ds], st[tile], 0, 0, 0);
      }

    // in-register online softmax (row is lane-local + partner half)
    float pmax = st[0][0];
#pragma unroll
    for (int r = 1; r < 16; ++r) pmax = fmaxf(pmax, st[0][r]);
#pragma unroll
    for (int r = 0; r < 16; ++r) pmax = fmaxf(pmax, st[1][r]);
    pmax = fmaxf(pmax, __shfl_xor(pmax, 32, 64));
    if (__any(pmax > mreg + 8.f)) {   // defer-max (T13)
      const float mn = fmaxf(mreg, pmax);
      const float al = __expf(mreg - mn);
      mreg = mn; lsum *= al;
#pragma unroll
      for (int d3 = 0; d3 < 3; ++d3)
#pragma unroll
        for (int r = 0; r < 16; ++r) oacc[d3][r] *= al;
    }
    float ts = 0.f;
    u32 wds[16];
#pragma unroll
    for (int g = 0; g < 8; ++g) {
      const float e0 = __expf(st[(4 * g) >> 4][(4 * g) & 15] - mreg);
      const float e1 = __expf(st[(4 * g + 1) >> 4][(4 * g + 1) & 15] - mreg);
      const float e2 = __expf(st[(4 * g + 2) >> 4][(4 * g + 2) & 15] - mreg);
      const float e3 = __expf(st[(4 * g + 3) >> 4][(4 * g + 3) & 15] - mreg);
      ts += (e0 + e1) + (e2 + e3);
      wds[2 * g]     = pk2(e0, e1);
      wds[2 * g + 1] = pk2(e2, e3);
    }
    ts += __shfl_xor(ts, 32, 64);
    lsum += ts;

    // O^T += V^T @ P^T ; P B-frag for step s = p[8s..8s+7] via 2 swaps
#pragma unroll
    for (int s = 0; s < 4; ++s) {
      i32x2 r02 = __builtin_amdgcn_permlane32_swap((int)wds[4 * s], (int)wds[4 * s + 2], false, false);
      i32x2 r13 = __builtin_amdgcn_permlane32_swap((int)wds[4 * s + 1], (int)wds[4 * s + 3], false, false);
      union { u32 wu[4]; bf16x8 v; } pu;
      pu.wu[0] = (u32)r02[0]; pu.wu[1] = (u32)r13[0];
      pu.wu[2] = (u32)r02[1]; pu.wu[3] = (u32)r13[1];
      const bf16x8 pf = pu.v;
#pragma unroll
      for (int d3 = 0; d3 < 3; ++d3) {
        const int row = d3 * 32 + lm;
        const int cs = (2 * s + hl) ^ (l & 7);
        bf16x8 vf = asbf(*(const u16x8*)(&sV[cur][row * 64 + cs * 8]));
        oacc[d3] = __builtin_amdgcn_mfma_f32_32x32x16_bf16(vf, pf, oacc[d3], 0, 0, 0);
      }
    }
    cur ^= 1;
  }

  // epilogue: O^T[d][q] -> obuf[b][tok][h*96+d], scaled by 1/(lsum*sqrt(768))
  const int b = p >> 3, h = p & 7;
  const float sc = 0.03608439182435161f / lsum;
  u16* ob = obuf + (size_t)(b * SEQ + q0w + lm) * EMB + h * HD;
#pragma unroll
  for (int d3 = 0; d3 < 3; ++d3)
#pragma unroll
    for (int g = 0; g < 4; ++g) {
      u16x4 o4;
#pragma unroll
      for (int j = 0; j < 4; ++j) o4[j] = f2bf(oacc[d3][4 * g + j] * sc);
      *(u16x4*)(ob + d3 * 32 + 8 * g + 4 * hl) = o4;
    }
#undef ASTAGE
}

// ---------------------------------------------------------------------------
extern "C" void kernel_launch(void* const* d_in, const int* in_sizes, int n_in,
                              void* d_out, int out_size, void* d_ws, size_t ws_size,
                              hipStream_t stream) {
  const float* x    = (const float*)d_in[0];
  const float* ln1g = (const float*)d_in[1];
  const float* ln1b = (const float*)d_in[2];
  const float* wq   = (const float*)d_in[3];
  const float* bq   = (const float*)d_in[4];
  const float* wk   = (const float*)d_in[5];
  const float* bk   = (const float*)d_in[6];
  const float* wv   = (const float*)d_in[7];
  const float* bv   = (const float*)d_in[8];
  const float* wo   = (const float*)d_in[9];
  const float* bo   = (const float*)d_in[10];
  const float* ln2g = (const float*)d_in[11];
  const float* ln2b = (const float*)d_in[12];
  const float* w1   = (const float*)d_in[13];
  const float* b1   = (const float*)d_in[14];
  const float* w2   = (const float*)d_in[15];
  const float* b2   = (const float*)d_in[16];
  float* out = (float*)d_out;

  char* ws = (char*)d_ws;
  u16* wqkvT  = (u16*)ws;   ws += (size_t)2304 * 768 * 2;
  u16* woT    = (u16*)ws;   ws += (size_t)768 * 768 * 2;
  u16* w1T    = (u16*)ws;   ws += (size_t)3072 * 768 * 2;
  u16* w2T    = (u16*)ws;   ws += (size_t)768 * 3072 * 2;
  float* bqkv = (float*)ws; ws += (size_t)2304 * 4;
  u16* bufA   = (u16*)ws;   ws += (size_t)NTOK * EMB * 2;   // y -> o -> z
  u16* bigbuf = (u16*)ws;   ws += (size_t)NTOK * DFF * 2;   // qkv -> ffn hidden
  float* x1   = (float*)ws; ws += (size_t)NTOK * EMB * 4;

  transpose_cvt<<<dim3(24, 24), 256, 0, stream>>>(wq, wqkvT, 768, 768);
  transpose_cvt<<<dim3(24, 24), 256, 0, stream>>>(wk, wqkvT + 768 * 768, 768, 768);
  transpose_cvt<<<dim3(24, 24), 256, 0, stream>>>(wv, wqkvT + 2 * 768 * 768, 768, 768);
  transpose_cvt<<<dim3(24, 24), 256, 0, stream>>>(wo, woT, 768, 768);
  transpose_cvt<<<dim3(96, 24), 256, 0, stream>>>(w1, w1T, 768, 3072);
  transpose_cvt<<<dim3(24, 96), 256, 0, stream>>>(w2, w2T, 3072, 768);
  concat_bias<<<9, 256, 0, stream>>>(bq, bk, bv, bqkv);

  ln_k<<<NTOK / 4, 256, 0, stream>>>(x, ln1g, ln1b, bufA);
  gemm_k<0><<<64 * 18, 256, 0, stream>>>(bufA, wqkvT, bqkv, nullptr, bigbuf,
                                         NTOK, 2304, 768, 18);
  attn_k<<<256, 512, 0, stream>>>(bigbuf, bufA);
  gemm_k<1><<<64 * 6, 256, 0, stream>>>(bufA, woT, bo, x, x1, NTOK, 768, 768, 6);
  ln_k<<<NTOK / 4, 256, 0, stream>>>(x1, ln2g, ln2b, bufA);
  gemm_k<2><<<64 * 24, 256, 0, stream>>>(bufA, w1T, b1, nullptr, bigbuf,
                                         NTOK, 3072, 768, 24);
  gemm_k<3><<<64 * 6, 256, 0, stream>>>(bigbuf, w2T, b2, x1, out, NTOK, 768, 3072, 6);
}

// Round 7
// 411.527 us; speedup vs baseline: 1.0790x; 1.0017x over previous
//
#include <hip/hip_runtime.h>
#include <math.h>

#define SEQ    2048
#define NBATCH 4
#define NTOK   8192
#define EMB    768
#define DFF    3072
#define NH     8
#define HD     96
#define QSEG   6291456   // 32 pairs * 2048 * 96

typedef float            f32x4  __attribute__((ext_vector_type(4)));
typedef float            f32x16 __attribute__((ext_vector_type(16)));
typedef __bf16           bf16x8 __attribute__((ext_vector_type(8)));
typedef unsigned short   u16;
typedef unsigned int     u32;
typedef int              i32x2  __attribute__((ext_vector_type(2)));
typedef u16              u16x8  __attribute__((ext_vector_type(8)));
typedef u16              u16x4  __attribute__((ext_vector_type(4)));

__device__ __forceinline__ u16 f2bf(float f) {
  union { float f; unsigned u; } v; v.f = f;
  unsigned r = v.u + 0x7FFFu + ((v.u >> 16) & 1u);
  return (u16)(r >> 16);
}
__device__ __forceinline__ bf16x8 asbf(u16x8 v) { return __builtin_bit_cast(bf16x8, v); }
__device__ __forceinline__ u32 pk2(float a, float b) {
  union { __bf16 h[2]; u32 w; } u; u.h[0] = (__bf16)a; u.h[1] = (__bf16)b; return u.w;
}

__device__ __forceinline__ void gload16(const void* g, void* l) {
  __builtin_amdgcn_global_load_lds((const __attribute__((address_space(1))) unsigned*)g,
                                   (__attribute__((address_space(3))) unsigned*)l, 16, 0, 0);
}

// ---------------------------------------------------------------------------
// Generic fp32 [R][C] -> bf16 transposed [C][R] (weights -> B^T bf16)
// ---------------------------------------------------------------------------
__global__ __launch_bounds__(256)
void transpose_cvt(const float* __restrict__ in, u16* __restrict__ out, int R, int C) {
  __shared__ float tile[32][33];
  const int c0 = blockIdx.x * 32, r0 = blockIdx.y * 32;
  const int tr = threadIdx.x >> 5, tc = threadIdx.x & 31;
#pragma unroll
  for (int i = 0; i < 4; ++i)
    tile[tr + 8 * i][tc] = in[(size_t)(r0 + tr + 8 * i) * C + c0 + tc];
  __syncthreads();
#pragma unroll
  for (int i = 0; i < 4; ++i)
    out[(size_t)(c0 + tr + 8 * i) * R + r0 + tc] = f2bf(tile[tc][tr + 8 * i]);
}

__global__ __launch_bounds__(256)
void concat_bias(const float* __restrict__ bq, const float* __restrict__ bk,
                 const float* __restrict__ bv, float* __restrict__ out) {
  int i = blockIdx.x * 256 + threadIdx.x;
  if (i < 2304) {
    const float* s = (i < 768) ? bq : ((i < 1536) ? bk : bv);
    out[i] = s[i % 768];
  }
}

// ---------------------------------------------------------------------------
// LayerNorm: fp32 [rows][768] -> bf16 [rows][768]; one wave per row
// ---------------------------------------------------------------------------
__global__ __launch_bounds__(256)
void ln_k(const float* __restrict__ x, const float* __restrict__ g,
          const float* __restrict__ b, u16* __restrict__ y) {
  const int row = blockIdx.x * 4 + (threadIdx.x >> 6);
  const int l = threadIdx.x & 63;
  const float* xr = x + (size_t)row * EMB;
  f32x4 v[3];
#pragma unroll
  for (int i = 0; i < 3; ++i) v[i] = *(const f32x4*)(xr + (l + 64 * i) * 4);
  float s = 0.f;
#pragma unroll
  for (int i = 0; i < 3; ++i)
#pragma unroll
    for (int j = 0; j < 4; ++j) s += v[i][j];
#pragma unroll
  for (int m = 32; m; m >>= 1) s += __shfl_xor(s, m, 64);
  const float mu = s * (1.0f / EMB);
  float q = 0.f;
#pragma unroll
  for (int i = 0; i < 3; ++i)
#pragma unroll
    for (int j = 0; j < 4; ++j) { float d = v[i][j] - mu; q += d * d; }
#pragma unroll
  for (int m = 32; m; m >>= 1) q += __shfl_xor(q, m, 64);
  const float rstd = rsqrtf(q * (1.0f / EMB) + 1e-5f);
#pragma unroll
  for (int i = 0; i < 3; ++i) {
    const int c0 = (l + 64 * i) * 4;
    f32x4 gv = *(const f32x4*)(g + c0);
    f32x4 bv = *(const f32x4*)(b + c0);
    u16x4 o;
#pragma unroll
    for (int j = 0; j < 4; ++j) o[j] = f2bf((v[i][j] - mu) * rstd * gv[j] + bv[j]);
    *(u16x4*)(y + (size_t)row * EMB + c0) = o;
  }
}

// ---------------------------------------------------------------------------
// GEMM v2: C[M][N] = A[M][K](bf16) @ B^T[N][K](bf16) + epilogue
// 128x256 tile, BK=32, 8 waves (2M x 4N), per-wave 64x64 (acc 4x4).
// Triple-buffered LDS (72KB -> 2 blocks/CU), depth-2 prefetch, counted
// vmcnt(3) (never 0 mid-loop), raw s_barrier, setprio around MFMA (T5).
// Ledger: iter t reads slot t%3; barrier A (readers done) -> stage tile t+3
// into slot t%3 -> vmcnt(3) (tile t+2 landed; t+3's 3 loads in flight) ->
// barrier B. Prologue stages tiles 0,1,2 + vmcnt(6) (tile 0 landed).
// EPI 0: +bias -> Q,K [p][tok][d] scatter; V via LDS-transpose -> [p][d][tok]
//        with full-line 16B stores (fixes write-allocate RMW inflation).
// EPI 1/3: +bias +resid -> fp32.   EPI 2: +bias, exact GELU -> bf16.
// ---------------------------------------------------------------------------
template <int EPI>
__global__ __launch_bounds__(512, 4)
void gemm2_k(const u16* __restrict__ A, const u16* __restrict__ BT,
             const float* __restrict__ bias, const float* __restrict__ resid,
             void* __restrict__ outp, int M, int N, int K, int nbn) {
  __shared__ __align__(16) u16 smem[36864];   // 72KB: sA 3x4096 | sB 3x8192
  u16* sA = smem;
  u16* sB = smem + 12288;
  const int t = threadIdx.x;
  const int w = t >> 6, l = t & 63;
  const int wr = w >> 2, wc = w & 3;
  const int lr = l & 15, lg = l >> 4;
  const int cpx = gridDim.x >> 3;
  const int bid = (blockIdx.x & 7) * cpx + (blockIdx.x >> 3);
  const int bm = bid / nbn, bn = bid - bm * nbn;
  const int m0 = bm << 7, n0 = bn << 8;

  // staging maps (pre-swizzled global source, linear LDS dest)
  const int rS = t >> 2, cS = t & 3;
  const int cSw = (cS ^ ((rS >> 1) & 3)) * 8;
  const u16* gA  = A  + (size_t)(m0 + rS) * K + cSw;
  const u16* gB0 = BT + (size_t)(n0 + rS) * K + cSw;
  const u16* gB1 = gB0 + (size_t)128 * K;     // rows +128: same swizzle ((r>>1)&3 invariant)
  u16* dA  = sA + t * 8;
  u16* dB0 = sB + t * 8;
  u16* dB1 = sB + 4096 + t * 8;

#define G2STAGE(slot, kel) {                     \
    gload16(gA  + (kel), dA  + (slot) * 4096);   \
    gload16(gB0 + (kel), dB0 + (slot) * 8192);   \
    gload16(gB1 + (kel), dB1 + (slot) * 8192); }

  const int swz = (lr >> 1) & 3;
  const int offA = (wr * 64 + lr) * 32 + ((lg ^ swz) * 8);  // + mf*512 + slot*4096
  const int offB = (wc * 64 + lr) * 32 + ((lg ^ swz) * 8);  // + nf*512 + slot*8192

  f32x4 acc[4][4] = {};
  G2STAGE(0, 0);
  G2STAGE(1, 32);
  G2STAGE(2, 64);
  asm volatile("s_waitcnt vmcnt(6)" ::: "memory");   // tile 0 landed
  __builtin_amdgcn_s_barrier();

  const int NT = K >> 5;
  int slot = 0;
  for (int ti = 0; ti < NT; ++ti) {
    bf16x8 af[4], bf[4];
#pragma unroll
    for (int mf = 0; mf < 4; ++mf)
      af[mf] = asbf(*(const u16x8*)(sA + slot * 4096 + offA + mf * 512));
#pragma unroll
    for (int nf = 0; nf < 4; ++nf)
      bf[nf] = asbf(*(const u16x8*)(sB + slot * 8192 + offB + nf * 512));
    __builtin_amdgcn_s_setprio(1);
#pragma unroll
    for (int mf = 0; mf < 4; ++mf)
#pragma unroll
      for (int nf = 0; nf < 4; ++nf)
        acc[mf][nf] = __builtin_amdgcn_mfma_f32_16x16x32_bf16(af[mf], bf[nf], acc[mf][nf], 0, 0, 0);
    __builtin_amdgcn_s_setprio(0);
    __builtin_amdgcn_s_barrier();                 // (A) all waves' reads of this slot retired
    if (ti + 3 < NT) {
      G2STAGE(slot, (ti + 3) * 32);               // depth-2: overwrite freed slot
      asm volatile("s_waitcnt vmcnt(3)" ::: "memory");
    } else if (ti + 2 == NT) {                    // ti == NT-2: last tile must land
      asm volatile("s_waitcnt vmcnt(0)" ::: "memory");
    }
    __builtin_amdgcn_s_barrier();                 // (B) next tile visible to all
    ++slot; if (slot == 3) slot = 0;
  }
#undef G2STAGE

  // epilogue: C/D frag layout col=lane&15, row=(lane>>4)*4+j
  if (EPI == 0) {
    const int whichB = n0 / 768;                  // block-uniform: 0=Q,1=K,2=V
    if (whichB < 2) {
      u16* qb = (u16*)outp + (size_t)whichB * QSEG;
#pragma unroll
      for (int nf = 0; nf < 4; ++nf) {
        const int col = n0 + wc * 64 + nf * 16 + lr;
        const int cm = col - whichB * 768;
        const int h = cm / 96, d = cm - h * 96;
        const float bcol = bias[col];
#pragma unroll
        for (int mf = 0; mf < 4; ++mf)
#pragma unroll
          for (int j = 0; j < 4; ++j) {
            const int row = m0 + wr * 64 + mf * 16 + lg * 4 + j;
            const int b = row >> 11, tok = row & 2047;
            qb[((size_t)((b * NH + h) * SEQ + tok)) * HD + d] = f2bf(acc[mf][nf][j] + bcol);
          }
      }
    } else {
      // V: LDS transpose -> V^T [p][d][tok], 16B full-line stores
      __syncthreads();
      u16* tp = smem;                             // [256 cols][136 rows pad]
      const int colb = wc * 64 + lr;
#pragma unroll
      for (int nf = 0; nf < 4; ++nf) {
        const float bcol = bias[n0 + colb + nf * 16];
#pragma unroll
        for (int mf = 0; mf < 4; ++mf) {
          u16x4 o4;
#pragma unroll
          for (int j = 0; j < 4; ++j) o4[j] = f2bf(acc[mf][nf][j] + bcol);
          *(u16x4*)(tp + (colb + nf * 16) * 136 + wr * 64 + mf * 16 + lg * 4) = o4;
        }
      }
      __syncthreads();
      const int c = t >> 1, half = t & 1;
      const int cm = n0 + c - 1536;
      const int h = cm / 96, d = cm - h * 96;
      const int b = m0 >> 11;
      const int tok0 = (m0 & 2047) + half * 64;
      u16* vb = (u16*)outp + 2 * (size_t)QSEG +
                ((size_t)((b * NH + h) * HD + d)) * SEQ + tok0;
      const u16* src = tp + c * 136 + half * 64;
#pragma unroll
      for (int i = 0; i < 8; ++i)
        *(u16x8*)(vb + i * 8) = *(const u16x8*)(src + i * 8);
    }
  } else {
#pragma unroll
    for (int nf = 0; nf < 4; ++nf) {
      const int col = n0 + wc * 64 + nf * 16 + lr;
      const float bcol = bias[col];
#pragma unroll
      for (int mf = 0; mf < 4; ++mf)
#pragma unroll
        for (int j = 0; j < 4; ++j) {
          const int row = m0 + wr * 64 + mf * 16 + lg * 4 + j;
          const float v = acc[mf][nf][j] + bcol;
          const size_t off = (size_t)row * N + col;
          if (EPI == 1 || EPI == 3) {
            ((float*)outp)[off] = v + resid[off];
          } else {
            ((u16*)outp)[off] = f2bf(0.5f * v * (1.0f + erff(v * 0.70710678f)));
          }
        }
    }
  }
}

// ---------------------------------------------------------------------------
// Flash attention, 8-warp swapped 32x32 structure (unchanged from R6).
// ---------------------------------------------------------------------------
__global__ __launch_bounds__(512, 2)
void attn_k(const u16* __restrict__ qkv, u16* __restrict__ obuf) {
  __shared__ __align__(16) u16 sK[2][64 * 128];
  __shared__ __align__(16) u16 sV[2][128 * 64];
  const int bid = blockIdx.x;
  const int x = bid & 7, i = bid >> 3;
  const int p = x * 4 + (i & 3), qt = i >> 2;
  const int t = threadIdx.x;
  const int w = t >> 6, l = t & 63;
  const int hl = l >> 5, lm = l & 31;
  const u16* qb  = qkv + (size_t)p * SEQ * HD;
  const u16* kb  = qb + QSEG;
  const u16* vtb = qkv + 2 * (size_t)QSEG + (size_t)p * SEQ * HD;
  const int q0w = qt * 256 + w * 32;

  bf16x8 qf[6];
#pragma unroll
  for (int ds = 0; ds < 6; ++ds)
    qf[ds] = asbf(*(const u16x8*)(qb + (size_t)(q0w + lm) * HD + ds * 16 + hl * 8));

  const int rK0 = t >> 4,        ccK0 = (t & 15) ^ (rK0 & 7);
  const int rK1 = 32 + (t >> 4), ccK1 = (t & 15) ^ (rK1 & 7);
  const int koff0 = rK0 * HD + ccK0 * 8;
  const int koff1 = rK1 * HD + ccK1 * 8;
  const int rV0 = t >> 3,        ccV0 = (t & 7) ^ (rV0 & 7);
  const int rV1 = 64 + (t >> 3), ccV1 = (t & 7) ^ (rV1 & 7);
  const int voff0 = rV0 * SEQ + ccV0 * 8;
  const int voff1 = rV1 * SEQ + ccV1 * 8;

#define ASTAGE(bi, kt_) {                                            \
    const u16* kbase = kb + (size_t)(kt_) * 64 * HD;                 \
    gload16(kbase + koff0, &sK[bi][t * 8]);                          \
    gload16(kbase + koff1, &sK[bi][4096 + t * 8]);                   \
    const u16* vbase = vtb + (kt_) * 64;                             \
    gload16(vbase + voff0, &sV[bi][t * 8]);                          \
    gload16(vbase + voff1, &sV[bi][4096 + t * 8]); }

  f32x16 oacc[3] = {};
  float mreg = -1e30f, lsum = 0.f;
  int cur = 0;

  ASTAGE(0, 0);
  for (int kt = 0; kt < 32; ++kt) {
    asm volatile("s_waitcnt vmcnt(0)" ::: "memory");
    __syncthreads();
    if (kt < 31) ASTAGE(cur ^ 1, kt + 1);

    f32x16 st[2] = {};
#pragma unroll
    for (int tile = 0; tile < 2; ++tile)
#pragma unroll
      for (int ds = 0; ds < 6; ++ds) {
        const int row = tile * 32 + lm;
        const int cs = (2 * ds + hl) ^ (l & 7);
        bf16x8 kf = asbf(*(const u16x8*)(&sK[cur][row * 128 + cs * 8]));
        st[tile] = __builtin_amdgcn_mfma_f32_32x32x16_bf16(kf, qf[ds], st[tile], 0, 0, 0);
      }

    float pmax = st[0][0];
#pragma unroll
    for (int r = 1; r < 16; ++r) pmax = fmaxf(pmax, st[0][r]);
#pragma unroll
    for (int r = 0; r < 16; ++r) pmax = fmaxf(pmax, st[1][r]);
    pmax = fmaxf(pmax, __shfl_xor(pmax, 32, 64));
    if (__any(pmax > mreg + 8.f)) {
      const float mn = fmaxf(mreg, pmax);
      const float al = __expf(mreg - mn);
      mreg = mn; lsum *= al;
#pragma unroll
      for (int d3 = 0; d3 < 3; ++d3)
#pragma unroll
        for (int r = 0; r < 16; ++r) oacc[d3][r] *= al;
    }
    float ts = 0.f;
    u32 wds[16];
#pragma unroll
    for (int g = 0; g < 8; ++g) {
      const float e0 = __expf(st[(4 * g) >> 4][(4 * g) & 15] - mreg);
      const float e1 = __expf(st[(4 * g + 1) >> 4][(4 * g + 1) & 15] - mreg);
      const float e2 = __expf(st[(4 * g + 2) >> 4][(4 * g + 2) & 15] - mreg);
      const float e3 = __expf(st[(4 * g + 3) >> 4][(4 * g + 3) & 15] - mreg);
      ts += (e0 + e1) + (e2 + e3);
      wds[2 * g]     = pk2(e0, e1);
      wds[2 * g + 1] = pk2(e2, e3);
    }
    ts += __shfl_xor(ts, 32, 64);
    lsum += ts;

#pragma unroll
    for (int s = 0; s < 4; ++s) {
      i32x2 r02 = __builtin_amdgcn_permlane32_swap((int)wds[4 * s], (int)wds[4 * s + 2], false, false);
      i32x2 r13 = __builtin_amdgcn_permlane32_swap((int)wds[4 * s + 1], (int)wds[4 * s + 3], false, false);
      union { u32 wu[4]; bf16x8 v; } pu;
      pu.wu[0] = (u32)r02[0]; pu.wu[1] = (u32)r13[0];
      pu.wu[2] = (u32)r02[1]; pu.wu[3] = (u32)r13[1];
      const bf16x8 pf = pu.v;
#pragma unroll
      for (int d3 = 0; d3 < 3; ++d3) {
        const int row = d3 * 32 + lm;
        const int cs = (2 * s + hl) ^ (l & 7);
        bf16x8 vf = asbf(*(const u16x8*)(&sV[cur][row * 64 + cs * 8]));
        oacc[d3] = __builtin_amdgcn_mfma_f32_32x32x16_bf16(vf, pf, oacc[d3], 0, 0, 0);
      }
    }
    cur ^= 1;
  }

  const int b = p >> 3, h = p & 7;
  const float sc = 0.03608439182435161f / lsum;
  u16* ob = obuf + (size_t)(b * SEQ + q0w + lm) * EMB + h * HD;
#pragma unroll
  for (int d3 = 0; d3 < 3; ++d3)
#pragma unroll
    for (int g = 0; g < 4; ++g) {
      u16x4 o4;
#pragma unroll
      for (int j = 0; j < 4; ++j) o4[j] = f2bf(oacc[d3][4 * g + j] * sc);
      *(u16x4*)(ob + d3 * 32 + 8 * g + 4 * hl) = o4;
    }
#undef ASTAGE
}

// ---------------------------------------------------------------------------
extern "C" void kernel_launch(void* const* d_in, const int* in_sizes, int n_in,
                              void* d_out, int out_size, void* d_ws, size_t ws_size,
                              hipStream_t stream) {
  const float* x    = (const float*)d_in[0];
  const float* ln1g = (const float*)d_in[1];
  const float* ln1b = (const float*)d_in[2];
  const float* wq   = (const float*)d_in[3];
  const float* bq   = (const float*)d_in[4];
  const float* wk   = (const float*)d_in[5];
  const float* bk   = (const float*)d_in[6];
  const float* wv   = (const float*)d_in[7];
  const float* bv   = (const float*)d_in[8];
  const float* wo   = (const float*)d_in[9];
  const float* bo   = (const float*)d_in[10];
  const float* ln2g = (const float*)d_in[11];
  const float* ln2b = (const float*)d_in[12];
  const float* w1   = (const float*)d_in[13];
  const float* b1   = (const float*)d_in[14];
  const float* w2   = (const float*)d_in[15];
  const float* b2   = (const float*)d_in[16];
  float* out = (float*)d_out;

  char* ws = (char*)d_ws;
  u16* wqkvT  = (u16*)ws;   ws += (size_t)2304 * 768 * 2;
  u16* woT    = (u16*)ws;   ws += (size_t)768 * 768 * 2;
  u16* w1T    = (u16*)ws;   ws += (size_t)3072 * 768 * 2;
  u16* w2T    = (u16*)ws;   ws += (size_t)768 * 3072 * 2;
  float* bqkv = (float*)ws; ws += (size_t)2304 * 4;
  u16* bufA   = (u16*)ws;   ws += (size_t)NTOK * EMB * 2;   // y -> o -> z
  u16* bigbuf = (u16*)ws;   ws += (size_t)NTOK * DFF * 2;   // qkv -> ffn hidden
  float* x1   = (float*)ws; ws += (size_t)NTOK * EMB * 4;

  transpose_cvt<<<dim3(24, 24), 256, 0, stream>>>(wq, wqkvT, 768, 768);
  transpose_cvt<<<dim3(24, 24), 256, 0, stream>>>(wk, wqkvT + 768 * 768, 768, 768);
  transpose_cvt<<<dim3(24, 24), 256, 0, stream>>>(wv, wqkvT + 2 * 768 * 768, 768, 768);
  transpose_cvt<<<dim3(24, 24), 256, 0, stream>>>(wo, woT, 768, 768);
  transpose_cvt<<<dim3(96, 24), 256, 0, stream>>>(w1, w1T, 768, 3072);
  transpose_cvt<<<dim3(24, 96), 256, 0, stream>>>(w2, w2T, 3072, 768);
  concat_bias<<<9, 256, 0, stream>>>(bq, bk, bv, bqkv);

  ln_k<<<NTOK / 4, 256, 0, stream>>>(x, ln1g, ln1b, bufA);
  // QKV projection (BN=256 tiles align wholly to Q/K/V segments)
  gemm2_k<0><<<576, 512, 0, stream>>>(bufA, wqkvT, bqkv, nullptr, bigbuf,
                                      NTOK, 2304, 768, 9);
  attn_k<<<256, 512, 0, stream>>>(bigbuf, bufA);
  gemm2_k<1><<<192, 512, 0, stream>>>(bufA, woT, bo, x, x1, NTOK, 768, 768, 3);
  ln_k<<<NTOK / 4, 256, 0, stream>>>(x1, ln2g, ln2b, bufA);
  gemm2_k<2><<<768, 512, 0, stream>>>(bufA, w1T, b1, nullptr, bigbuf,
                                      NTOK, 3072, 768, 12);
  gemm2_k<3><<<192, 512, 0, stream>>>(bigbuf, w2T, b2, x1, out, NTOK, 768, 3072, 3);
}